// Round 4
// baseline (443.252 us; speedup 1.0000x reference)
//
#include <hip/hip_runtime.h>

#define NCH 32
#define INCH 128
#define SH 7                  // nodes per coarse bucket = 128
#define BNODES 128
#define CAP 4544              // per-bucket capacity: avg 4092 + ~7 sigma
#define P1_CHUNK 8192
#define NBINS_PAD 1024        // coarse buckets padded for scan (N <= 131072)
#define NTILES 8              // src tiles of 16384 nodes (2 MB fp32 slice)
#define NB2 (BNODES * NTILES) // 1024 fine bins in bucket sort
#define AGG_BLOCKS 2048       // co-resident persistent grid for agg kernels
#define SLOTS 7               // node slots per 32-lane group: 8*7=56 >= ceil(N/2048)

// ---- init per-bucket write cursors ------------------------------------------
__global__ void k_initcur(int* gcur, int nbk) {
  int i = blockIdx.x * blockDim.x + threadIdx.x;
  if (i < nbk) gcur[i] = i * CAP;
}

// ---- P1: block-local counting sort into coarse buckets, chunked copy-out ----
__global__ __launch_bounds__(256) void k_part(const int* __restrict__ ei, int* gcur,
                                              unsigned int* __restrict__ srcsb, int E) {
  __shared__ unsigned int sorted[P1_CHUNK];
  __shared__ int hist[NBINS_PAD];       // counts, later reused to hold global dest
  __shared__ int bbase[NBINS_PAD + 1];
  __shared__ int bfill[NBINS_PAD];
  __shared__ int wsums[4];
  const int tid = threadIdx.x;
  const int base = blockIdx.x * P1_CHUNK;
  const int cnt = min(P1_CHUNK, E - base);

  for (int i = tid; i < NBINS_PAD; i += 256) hist[i] = 0;
  __syncthreads();
  for (int i = tid; i < cnt; i += 256) {
    int d = ei[E + base + i];
    atomicAdd(&hist[d >> SH], 1);
  }
  __syncthreads();
  int c0 = hist[4 * tid], c1 = hist[4 * tid + 1], c2 = hist[4 * tid + 2], c3 = hist[4 * tid + 3];
  int s = c0 + c1 + c2 + c3;
  int lane = tid & 63, w = tid >> 6;
  int incl = s;
#pragma unroll
  for (int off = 1; off < 64; off <<= 1) {
    int t = __shfl_up(incl, off, 64);
    if (lane >= off) incl += t;
  }
  if (lane == 63) wsums[w] = incl;
  __syncthreads();
  int woff = 0;
  for (int i = 0; i < w; ++i) woff += wsums[i];
  int te = woff + incl - s;
  bbase[4 * tid] = te;                     bfill[4 * tid] = te;
  bbase[4 * tid + 1] = te + c0;            bfill[4 * tid + 1] = te + c0;
  bbase[4 * tid + 2] = te + c0 + c1;       bfill[4 * tid + 2] = te + c0 + c1;
  bbase[4 * tid + 3] = te + c0 + c1 + c2;  bfill[4 * tid + 3] = te + c0 + c1 + c2;
  if (tid == 255) bbase[NBINS_PAD] = te + s;
  __syncthreads();
  for (int i = tid; i < cnt; i += 256) {
    int d = ei[E + base + i];
    int srcv = ei[base + i];
    int b = d >> SH;
    int pos = atomicAdd(&bfill[b], 1);
    sorted[pos] = ((unsigned int)(d & (BNODES - 1)) << 17) | (unsigned int)srcv;
  }
  __syncthreads();
  for (int b = tid; b < NBINS_PAD; b += 256) {
    int c = bbase[b + 1] - bbase[b];
    hist[b] = (c > 0) ? atomicAdd(&gcur[b], c) : 0;
  }
  __syncthreads();
  for (int i = tid; i < cnt; i += 256) {
    int lo = 0, hi = NBINS_PAD - 1;
#pragma unroll
    for (int it = 0; it < 10; ++it) {
      int mid = (lo + hi + 1) >> 1;
      if (bbase[mid] <= i) lo = mid; else hi = mid - 1;
    }
    int gpos = hist[lo] + (i - bbase[lo]);
    if (gpos < (lo + 1) * CAP) srcsb[gpos] = sorted[i];  // clamp vs overflow
  }
}

// ---- P2: per-bucket counting sort by (node, src-tile); emit segb/rowend/dis --
__global__ __launch_bounds__(256) void k_bsort(const int* __restrict__ gcur,
                                               unsigned int* __restrict__ srcsb,
                                               int* __restrict__ segb, int* __restrict__ rowend,
                                               float* __restrict__ dis, int N) {
  __shared__ unsigned int raw[CAP];
  __shared__ unsigned int sbuf[CAP];
  __shared__ int hist[NB2];
  __shared__ int sce[NB2 + 1];
  __shared__ int fill[NB2];
  __shared__ int wsums[4];
  const int tid = threadIdx.x;
  const int bin = blockIdx.x;
  const int base = bin * CAP;
  int cnt = min(gcur[bin] - base, CAP);

  for (int i = tid; i < NB2; i += 256) hist[i] = 0;
  for (int i = tid; i < cnt; i += 256) raw[i] = srcsb[base + i];
  __syncthreads();
  for (int i = tid; i < cnt; i += 256) {
    unsigned int v = raw[i];
    atomicAdd(&hist[((v >> 17) << 3) | ((v & 0x1FFFFu) >> 14)], 1);
  }
  __syncthreads();
  int c0 = hist[4 * tid], c1 = hist[4 * tid + 1], c2 = hist[4 * tid + 2], c3 = hist[4 * tid + 3];
  int s = c0 + c1 + c2 + c3;
  int lane = tid & 63, w = tid >> 6;
  int incl = s;
#pragma unroll
  for (int off = 1; off < 64; off <<= 1) {
    int t = __shfl_up(incl, off, 64);
    if (lane >= off) incl += t;
  }
  if (lane == 63) wsums[w] = incl;
  __syncthreads();
  int woff = 0;
  for (int i = 0; i < w; ++i) woff += wsums[i];
  int te = woff + incl - s;
  sce[4 * tid] = te;                     fill[4 * tid] = te;
  sce[4 * tid + 1] = te + c0;            fill[4 * tid + 1] = te + c0;
  sce[4 * tid + 2] = te + c0 + c1;       fill[4 * tid + 2] = te + c0 + c1;
  sce[4 * tid + 3] = te + c0 + c1 + c2;  fill[4 * tid + 3] = te + c0 + c1 + c2;
  if (tid == 255) sce[NB2] = te + s;     // == cnt
  __syncthreads();
  for (int i = tid; i < cnt; i += 256) {
    unsigned int v = raw[i];
    int b = (int)(((v >> 17) << 3) | ((v & 0x1FFFFu) >> 14));
    int pos = atomicAdd(&fill[b], 1);
    sbuf[pos] = v & 0x1FFFFu;
  }
  __syncthreads();
  for (int i = tid; i < cnt; i += 256) srcsb[base + i] = sbuf[i];  // coalesced
#pragma unroll
  for (int k = 0; k < 4; ++k) {
    int idx = 4 * tid + k;
    int dl = idx >> 3, tt = idx & 7;
    int n = bin * BNODES + dl;
    if (n < N) {
      segb[(size_t)n * NTILES + tt] = base + sce[idx];
      if (tt == 7) rowend[n] = base + sce[idx + 1];
    }
  }
  if (tid < BNODES) {
    int n = bin * BNODES + tid;
    if (n < N) {
      int deg = sce[tid * NTILES + NTILES] - sce[tid * NTILES];
      dis[n] = rsqrtf((float)(deg + 1));
    }
  }
}

// ---- layer 1 linear: hs[n][c] = (x[n]·W1[:,c]) * dis[n] ---------------------
__global__ __launch_bounds__(256) void k_gemm1(const float* __restrict__ x,
                                               const float* __restrict__ W1,
                                               const float* __restrict__ dis,
                                               float* __restrict__ hs, int N) {
  __shared__ float w[INCH * NCH];
  for (int i = threadIdx.x; i < INCH * NCH; i += blockDim.x) w[i] = W1[i];
  __syncthreads();
  int t = blockIdx.x * blockDim.x + threadIdx.x;
  int n = t >> 5, c = t & 31;
  if (n >= N) return;
  const float* xr = x + (size_t)n * INCH;
  float acc = 0.f;
#pragma unroll
  for (int k = 0; k < INCH; ++k) acc = fmaf(xr[k], w[k * NCH + c], acc);
  hs[(size_t)n * NCH + c] = acc * dis[n];
}

// ---- tile-paced gather-aggregate core (acc in registers) --------------------
__device__ __forceinline__ void agg_tiles(const int* __restrict__ segb,
                                          const int* __restrict__ rowend,
                                          const unsigned int* __restrict__ srcs,
                                          const float* __restrict__ hs,
                                          int beg, int end, int g, int c,
                                          float acc[SLOTS]) {
#pragma unroll
  for (int sl = 0; sl < SLOTS; ++sl) {
    int n = beg + sl * 8 + g;
    acc[sl] = (n < end) ? hs[(size_t)n * NCH + c] : 0.f;  // self loop
  }
  for (int t = 0; t < NTILES; ++t) {
#pragma unroll
    for (int sl = 0; sl < SLOTS; ++sl) {
      int n = beg + sl * 8 + g;
      if (n >= end) continue;
      int j = segb[(size_t)n * NTILES + t];
      int e = (t < NTILES - 1) ? segb[(size_t)n * NTILES + t + 1] : rowend[n];
      float a = acc[sl];
      for (; j + 4 <= e; j += 4) {
        unsigned int s0 = srcs[j], s1 = srcs[j + 1], s2 = srcs[j + 2], s3 = srcs[j + 3];
        float a0 = hs[(size_t)s0 * NCH + c];
        float a1 = hs[(size_t)s1 * NCH + c];
        float a2 = hs[(size_t)s2 * NCH + c];
        float a3 = hs[(size_t)s3 * NCH + c];
        a += (a0 + a1) + (a2 + a3);
      }
      for (; j < e; ++j) a += hs[(size_t)srcs[j] * NCH + c];
      acc[sl] = a;
    }
    __syncthreads();  // pace the block's waves tile-by-tile for L2 residency
  }
}

// ---- agg1 + layer-2 linear fused: hs2 = (relu(dis*(self+Σ)+b1) @ W2) * dis --
__global__ __launch_bounds__(256) void k_agg1g2(
    const int* __restrict__ segb, const int* __restrict__ rowend,
    const unsigned int* __restrict__ srcs, const float* __restrict__ hs,
    const float* __restrict__ dis, const float* __restrict__ b1,
    const float* __restrict__ W2, float* __restrict__ hs2, int N, int npb) {
  __shared__ float w[NCH * NCH];
  for (int i = threadIdx.x; i < NCH * NCH; i += blockDim.x) w[i] = W2[i];
  __syncthreads();
  int beg = blockIdx.x * npb;
  int end = min(beg + npb, N);
  int g = threadIdx.x >> 5, c = threadIdx.x & 31;
  float acc[SLOTS];
  agg_tiles(segb, rowend, srcs, hs, beg, end, g, c, acc);
#pragma unroll
  for (int sl = 0; sl < SLOTS; ++sl) {
    int n = beg + sl * 8 + g;
    if (n >= end) continue;
    float dn = dis[n];
    float v = fmaxf(fmaf(acc[sl], dn, b1[c]), 0.f);
    float acc2 = 0.f;
#pragma unroll
    for (int k = 0; k < NCH; ++k) acc2 = fmaf(__shfl(v, k, 32), w[k * NCH + c], acc2);
    hs2[(size_t)n * NCH + c] = acc2 * dn;
  }
}

// ---- agg2 + head: v=relu(dis*(self+Σ)+b2); out[n] = v·Wc + bc ---------------
__global__ __launch_bounds__(256) void k_agg2h(
    const int* __restrict__ segb, const int* __restrict__ rowend,
    const unsigned int* __restrict__ srcs, const float* __restrict__ hs2,
    const float* __restrict__ dis, const float* __restrict__ b2,
    const float* __restrict__ Wc, const float* __restrict__ bc,
    float* __restrict__ out, int N, int npb) {
  int beg = blockIdx.x * npb;
  int end = min(beg + npb, N);
  int g = threadIdx.x >> 5, c = threadIdx.x & 31;
  float acc[SLOTS];
  agg_tiles(segb, rowend, srcs, hs2, beg, end, g, c, acc);
  float wc0 = Wc[c * 2 + 0], wc1 = Wc[c * 2 + 1];
#pragma unroll
  for (int sl = 0; sl < SLOTS; ++sl) {
    int n = beg + sl * 8 + g;
    if (n >= end) continue;
    float v = fmaxf(fmaf(acc[sl], dis[n], b2[c]), 0.f);
    float s0 = v * wc0;
    float s1 = v * wc1;
#pragma unroll
    for (int off = 16; off > 0; off >>= 1) {
      s0 += __shfl_down(s0, off, 32);
      s1 += __shfl_down(s1, off, 32);
    }
    if (c == 0) {
      out[(size_t)n * 2 + 0] = s0 + bc[0];
      out[(size_t)n * 2 + 1] = s1 + bc[1];
    }
  }
}

extern "C" void kernel_launch(void* const* d_in, const int* in_sizes, int n_in,
                              void* d_out, int out_size, void* d_ws, size_t ws_size,
                              hipStream_t stream) {
  const float* x  = (const float*)d_in[0];
  const int*   ei = (const int*)d_in[1];
  const float* W1 = (const float*)d_in[2];
  const float* b1 = (const float*)d_in[3];
  const float* W2 = (const float*)d_in[4];
  const float* b2 = (const float*)d_in[5];
  const float* Wc = (const float*)d_in[6];
  const float* bc = (const float*)d_in[7];
  float* out = (float*)d_out;

  const int N = in_sizes[0] / INCH;  // 100000
  const int E = in_sizes[1] / 2;     // 3200000
  const int nbk = (N + BNODES - 1) / BNODES;  // 782

  // workspace layout (4B elems)
  float*        dis    = (float*)d_ws;                       // N
  int*          rowend = (int*)(dis + N);                    // N
  int*          segb   = rowend + N;                         // N*8
  int*          gcur   = segb + (size_t)N * NTILES;          // nbk
  unsigned int* srcsb  = (unsigned int*)(gcur + nbk);        // nbk*CAP
  float*        bufA   = (float*)(srcsb + (size_t)nbk * CAP);// N*32
  float*        bufB   = bufA + (size_t)N * NCH;             // N*32

  const int bn = 256;
  const int gN32 = (int)(((long long)N * NCH + bn - 1) / bn);
  const int gP1  = (E + P1_CHUNK - 1) / P1_CHUNK;  // 391
  const int npb  = (N + AGG_BLOCKS - 1) / AGG_BLOCKS;  // 49 (<= SLOTS*8)

  k_initcur<<<(nbk + bn - 1) / bn, bn, 0, stream>>>(gcur, nbk);
  k_part<<<gP1, bn, 0, stream>>>(ei, gcur, srcsb, E);
  k_bsort<<<nbk, bn, 0, stream>>>(gcur, srcsb, segb, rowend, dis, N);

  k_gemm1<<<gN32, bn, 0, stream>>>(x, W1, dis, bufA, N);
  k_agg1g2<<<AGG_BLOCKS, bn, 0, stream>>>(segb, rowend, srcsb, bufA, dis, b1, W2, bufB, N, npb);
  k_agg2h<<<AGG_BLOCKS, bn, 0, stream>>>(segb, rowend, srcsb, bufB, dis, b2, Wc, bc, out, N, npb);
}

// Round 5
// 212.623 us; speedup vs baseline: 2.0847x; 2.0847x over previous
//
#include <hip/hip_runtime.h>

#define NCH 32
#define INCH 128
#define SH 7                  // nodes per coarse bucket = 128
#define BNODES 128
#define CAP 4544              // per-bucket capacity: avg 4092 + ~7 sigma
#define P1_CHUNK 8192
#define NBINS_PAD 1024        // coarse buckets padded for scan (N <= 131072)
#define HCH 16                // uints per node row (2 bf16 channels per uint)

// ---- bf16 pack/unpack (RNE) -------------------------------------------------
__device__ __forceinline__ unsigned int pack_bf16x2(float a, float b) {
  unsigned int ua = __float_as_uint(a);
  unsigned int ub = __float_as_uint(b);
  ua = (ua + 0x7FFFu + ((ua >> 16) & 1u)) >> 16;
  ub = (ub + 0x7FFFu + ((ub >> 16) & 1u)) & 0xFFFF0000u;
  return ub | ua;
}
__device__ __forceinline__ float lo_bf16(unsigned int u) { return __uint_as_float(u << 16); }
__device__ __forceinline__ float hi_bf16(unsigned int u) { return __uint_as_float(u & 0xFFFF0000u); }

// ---- init per-bucket write cursors ------------------------------------------
__global__ void k_initcur(int* gcur, int nbk) {
  int i = blockIdx.x * blockDim.x + threadIdx.x;
  if (i < nbk) gcur[i] = i * CAP;
}

// ---- P1: block-local counting sort into coarse buckets, chunked copy-out ----
__global__ __launch_bounds__(256) void k_part(const int* __restrict__ ei, int* gcur,
                                              unsigned int* __restrict__ srcsb, int E) {
  __shared__ unsigned int sorted[P1_CHUNK];
  __shared__ int hist[NBINS_PAD];       // counts, later reused to hold global dest
  __shared__ int bbase[NBINS_PAD + 1];
  __shared__ int bfill[NBINS_PAD];
  __shared__ int wsums[4];
  const int tid = threadIdx.x;
  const int base = blockIdx.x * P1_CHUNK;
  const int cnt = min(P1_CHUNK, E - base);

  for (int i = tid; i < NBINS_PAD; i += 256) hist[i] = 0;
  __syncthreads();
  for (int i = tid; i < cnt; i += 256) {
    int d = ei[E + base + i];
    atomicAdd(&hist[d >> SH], 1);
  }
  __syncthreads();
  int c0 = hist[4 * tid], c1 = hist[4 * tid + 1], c2 = hist[4 * tid + 2], c3 = hist[4 * tid + 3];
  int s = c0 + c1 + c2 + c3;
  int lane = tid & 63, w = tid >> 6;
  int incl = s;
#pragma unroll
  for (int off = 1; off < 64; off <<= 1) {
    int t = __shfl_up(incl, off, 64);
    if (lane >= off) incl += t;
  }
  if (lane == 63) wsums[w] = incl;
  __syncthreads();
  int woff = 0;
  for (int i = 0; i < w; ++i) woff += wsums[i];
  int te = woff + incl - s;
  bbase[4 * tid] = te;                     bfill[4 * tid] = te;
  bbase[4 * tid + 1] = te + c0;            bfill[4 * tid + 1] = te + c0;
  bbase[4 * tid + 2] = te + c0 + c1;       bfill[4 * tid + 2] = te + c0 + c1;
  bbase[4 * tid + 3] = te + c0 + c1 + c2;  bfill[4 * tid + 3] = te + c0 + c1 + c2;
  if (tid == 255) bbase[NBINS_PAD] = te + s;
  __syncthreads();
  for (int i = tid; i < cnt; i += 256) {
    int d = ei[E + base + i];
    int srcv = ei[base + i];
    int b = d >> SH;
    int pos = atomicAdd(&bfill[b], 1);
    sorted[pos] = ((unsigned int)(d & (BNODES - 1)) << 17) | (unsigned int)srcv;
  }
  __syncthreads();
  for (int b = tid; b < NBINS_PAD; b += 256) {
    int c = bbase[b + 1] - bbase[b];
    hist[b] = (c > 0) ? atomicAdd(&gcur[b], c) : 0;
  }
  __syncthreads();
  for (int i = tid; i < cnt; i += 256) {
    int lo = 0, hi = NBINS_PAD - 1;
#pragma unroll
    for (int it = 0; it < 10; ++it) {
      int mid = (lo + hi + 1) >> 1;
      if (bbase[mid] <= i) lo = mid; else hi = mid - 1;
    }
    int gpos = hist[lo] + (i - bbase[lo]);
    if (gpos < (lo + 1) * CAP) srcsb[gpos] = sorted[i];  // clamp vs overflow
  }
}

// ---- P2: per-bucket counting sort by node; emit rowbeg/rowend/dis ------------
__global__ __launch_bounds__(256) void k_bsort(const int* __restrict__ gcur,
                                               unsigned int* __restrict__ srcsb,
                                               int* __restrict__ rowbeg, int* __restrict__ rowend,
                                               float* __restrict__ dis, int N) {
  __shared__ unsigned int raw[CAP];
  __shared__ unsigned int sbuf[CAP];
  __shared__ int hist2[BNODES];
  __shared__ int sc[BNODES];
  __shared__ int fill2[BNODES];
  const int tid = threadIdx.x;
  const int bin = blockIdx.x;
  const int base = bin * CAP;
  int cnt = min(gcur[bin] - base, CAP);

  if (tid < BNODES) hist2[tid] = 0;
  for (int i = tid; i < cnt; i += 256) raw[i] = srcsb[base + i];
  __syncthreads();
  for (int i = tid; i < cnt; i += 256) atomicAdd(&hist2[raw[i] >> 17], 1);
  __syncthreads();
  int deg = (tid < BNODES) ? hist2[tid] : 0;
  if (tid < BNODES) sc[tid] = deg;
  __syncthreads();
  for (int off = 1; off < BNODES; off <<= 1) {
    int t = 0;
    if (tid < BNODES && tid >= off) t = sc[tid - off];
    __syncthreads();
    if (tid < BNODES) sc[tid] += t;
    __syncthreads();
  }
  int excl = 0;
  if (tid < BNODES) { excl = sc[tid] - deg; fill2[tid] = excl; }
  __syncthreads();
  for (int i = tid; i < cnt; i += 256) {
    unsigned int v = raw[i];
    int pos = atomicAdd(&fill2[v >> 17], 1);
    sbuf[pos] = v & 0x1FFFFu;
  }
  __syncthreads();
  for (int i = tid; i < cnt; i += 256) srcsb[base + i] = sbuf[i];  // coalesced
  if (tid < BNODES) {
    int n = bin * BNODES + tid;
    if (n < N) {
      rowbeg[n] = base + excl;
      rowend[n] = base + excl + deg;
      dis[n] = rsqrtf((float)(deg + 1));
    }
  }
}

// ---- layer 1 linear: hs[n][2c2..2c2+1] = (x[n]·W1) * dis[n], bf16 packed ----
__global__ __launch_bounds__(256) void k_gemm1(const float* __restrict__ x,
                                               const float* __restrict__ W1,
                                               const float* __restrict__ dis,
                                               unsigned int* __restrict__ hs, int N) {
  __shared__ float w[INCH * NCH];
  for (int i = threadIdx.x; i < INCH * NCH; i += blockDim.x) w[i] = W1[i];
  __syncthreads();
  int n = blockIdx.x * 16 + (threadIdx.x >> 4);
  int c2 = threadIdx.x & 15;
  if (n >= N) return;
  const float* xr = x + (size_t)n * INCH;
  float ax = 0.f, ay = 0.f;
#pragma unroll
  for (int k = 0; k < INCH; ++k) {
    float xv = xr[k];
    float2 ww = ((const float2*)(w + k * NCH))[c2];
    ax = fmaf(xv, ww.x, ax);
    ay = fmaf(xv, ww.y, ay);
  }
  float dn = dis[n];
  hs[(size_t)n * HCH + c2] = pack_bf16x2(ax * dn, ay * dn);
}

// ---- agg1 + layer-2 linear fused (bf16 tables, fp32 accum) ------------------
__global__ __launch_bounds__(256) void k_agg1g2(
    const int* __restrict__ rowbeg, const int* __restrict__ rowend,
    const unsigned int* __restrict__ srcs, const unsigned int* __restrict__ hs,
    const float* __restrict__ dis, const float* __restrict__ b1,
    const float* __restrict__ W2, unsigned int* __restrict__ hs2, int N) {
  __shared__ float w[NCH * NCH];
  for (int i = threadIdx.x; i < NCH * NCH; i += blockDim.x) w[i] = W2[i];
  __syncthreads();
  int n = blockIdx.x * 16 + (threadIdx.x >> 4);
  int c2 = threadIdx.x & 15;
  if (n >= N) return;
  int j = rowbeg[n], end = rowend[n];
  unsigned int su = hs[(size_t)n * HCH + c2];
  float ax = lo_bf16(su), ay = hi_bf16(su);  // self loop
  for (; j + 8 <= end; j += 8) {
    unsigned int u0 = hs[(size_t)srcs[j] * HCH + c2];
    unsigned int u1 = hs[(size_t)srcs[j + 1] * HCH + c2];
    unsigned int u2 = hs[(size_t)srcs[j + 2] * HCH + c2];
    unsigned int u3 = hs[(size_t)srcs[j + 3] * HCH + c2];
    unsigned int u4 = hs[(size_t)srcs[j + 4] * HCH + c2];
    unsigned int u5 = hs[(size_t)srcs[j + 5] * HCH + c2];
    unsigned int u6 = hs[(size_t)srcs[j + 6] * HCH + c2];
    unsigned int u7 = hs[(size_t)srcs[j + 7] * HCH + c2];
    ax += ((lo_bf16(u0) + lo_bf16(u1)) + (lo_bf16(u2) + lo_bf16(u3))) +
          ((lo_bf16(u4) + lo_bf16(u5)) + (lo_bf16(u6) + lo_bf16(u7)));
    ay += ((hi_bf16(u0) + hi_bf16(u1)) + (hi_bf16(u2) + hi_bf16(u3))) +
          ((hi_bf16(u4) + hi_bf16(u5)) + (hi_bf16(u6) + hi_bf16(u7)));
  }
  for (; j < end; ++j) {
    unsigned int u = hs[(size_t)srcs[j] * HCH + c2];
    ax += lo_bf16(u);
    ay += hi_bf16(u);
  }
  float dn = dis[n];
  float v0 = fmaxf(fmaf(ax, dn, b1[2 * c2]), 0.f);
  float v1 = fmaxf(fmaf(ay, dn, b1[2 * c2 + 1]), 0.f);
  float o0 = 0.f, o1 = 0.f;
#pragma unroll
  for (int k2 = 0; k2 < 16; ++k2) {
    float a = __shfl(v0, k2, 16);
    float b = __shfl(v1, k2, 16);
    float2 wa = ((const float2*)(w + (2 * k2) * NCH))[c2];
    float2 wb = ((const float2*)(w + (2 * k2 + 1) * NCH))[c2];
    o0 = fmaf(a, wa.x, fmaf(b, wb.x, o0));
    o1 = fmaf(a, wa.y, fmaf(b, wb.y, o1));
  }
  hs2[(size_t)n * HCH + c2] = pack_bf16x2(o0 * dn, o1 * dn);
}

// ---- agg2 + head: v=relu(dis*(self+Σ)+b2); out[n] = v·Wc + bc ---------------
__global__ __launch_bounds__(256) void k_agg2h(
    const int* __restrict__ rowbeg, const int* __restrict__ rowend,
    const unsigned int* __restrict__ srcs, const unsigned int* __restrict__ hs2,
    const float* __restrict__ dis, const float* __restrict__ b2,
    const float* __restrict__ Wc, const float* __restrict__ bc,
    float* __restrict__ out, int N) {
  int n = blockIdx.x * 16 + (threadIdx.x >> 4);
  int c2 = threadIdx.x & 15;
  if (n >= N) return;
  int j = rowbeg[n], end = rowend[n];
  unsigned int su = hs2[(size_t)n * HCH + c2];
  float ax = lo_bf16(su), ay = hi_bf16(su);
  for (; j + 8 <= end; j += 8) {
    unsigned int u0 = hs2[(size_t)srcs[j] * HCH + c2];
    unsigned int u1 = hs2[(size_t)srcs[j + 1] * HCH + c2];
    unsigned int u2 = hs2[(size_t)srcs[j + 2] * HCH + c2];
    unsigned int u3 = hs2[(size_t)srcs[j + 3] * HCH + c2];
    unsigned int u4 = hs2[(size_t)srcs[j + 4] * HCH + c2];
    unsigned int u5 = hs2[(size_t)srcs[j + 5] * HCH + c2];
    unsigned int u6 = hs2[(size_t)srcs[j + 6] * HCH + c2];
    unsigned int u7 = hs2[(size_t)srcs[j + 7] * HCH + c2];
    ax += ((lo_bf16(u0) + lo_bf16(u1)) + (lo_bf16(u2) + lo_bf16(u3))) +
          ((lo_bf16(u4) + lo_bf16(u5)) + (lo_bf16(u6) + lo_bf16(u7)));
    ay += ((hi_bf16(u0) + hi_bf16(u1)) + (hi_bf16(u2) + hi_bf16(u3))) +
          ((hi_bf16(u4) + hi_bf16(u5)) + (hi_bf16(u6) + hi_bf16(u7)));
  }
  for (; j < end; ++j) {
    unsigned int u = hs2[(size_t)srcs[j] * HCH + c2];
    ax += lo_bf16(u);
    ay += hi_bf16(u);
  }
  float dn = dis[n];
  float v0 = fmaxf(fmaf(ax, dn, b2[2 * c2]), 0.f);
  float v1 = fmaxf(fmaf(ay, dn, b2[2 * c2 + 1]), 0.f);
  float s0 = v0 * Wc[(2 * c2) * 2 + 0] + v1 * Wc[(2 * c2 + 1) * 2 + 0];
  float s1 = v0 * Wc[(2 * c2) * 2 + 1] + v1 * Wc[(2 * c2 + 1) * 2 + 1];
#pragma unroll
  for (int off = 8; off > 0; off >>= 1) {
    s0 += __shfl_down(s0, off, 16);
    s1 += __shfl_down(s1, off, 16);
  }
  if (c2 == 0) {
    out[(size_t)n * 2 + 0] = s0 + bc[0];
    out[(size_t)n * 2 + 1] = s1 + bc[1];
  }
}

extern "C" void kernel_launch(void* const* d_in, const int* in_sizes, int n_in,
                              void* d_out, int out_size, void* d_ws, size_t ws_size,
                              hipStream_t stream) {
  const float* x  = (const float*)d_in[0];
  const int*   ei = (const int*)d_in[1];
  const float* W1 = (const float*)d_in[2];
  const float* b1 = (const float*)d_in[3];
  const float* W2 = (const float*)d_in[4];
  const float* b2 = (const float*)d_in[5];
  const float* Wc = (const float*)d_in[6];
  const float* bc = (const float*)d_in[7];
  float* out = (float*)d_out;

  const int N = in_sizes[0] / INCH;  // 100000
  const int E = in_sizes[1] / 2;     // 3200000
  const int nbk = (N + BNODES - 1) / BNODES;  // 782

  // workspace layout (4B elems)
  float*        dis    = (float*)d_ws;                       // N
  int*          rowbeg = (int*)(dis + N);                    // N
  int*          rowend = rowbeg + N;                         // N
  int*          gcur   = rowend + N;                         // nbk
  unsigned int* srcsb  = (unsigned int*)(gcur + nbk);        // nbk*CAP
  unsigned int* bufA   = srcsb + (size_t)nbk * CAP;          // N*16 (bf16x2)
  unsigned int* bufB   = bufA + (size_t)N * HCH;             // N*16 (bf16x2)

  const int bn = 256;
  const int gP1  = (E + P1_CHUNK - 1) / P1_CHUNK;      // 391
  const int gN16 = (N + 15) / 16;                      // 6250

  k_initcur<<<(nbk + bn - 1) / bn, bn, 0, stream>>>(gcur, nbk);
  k_part<<<gP1, bn, 0, stream>>>(ei, gcur, srcsb, E);
  k_bsort<<<nbk, bn, 0, stream>>>(gcur, srcsb, rowbeg, rowend, dis, N);

  k_gemm1<<<gN16, bn, 0, stream>>>(x, W1, dis, bufA, N);
  k_agg1g2<<<gN16, bn, 0, stream>>>(rowbeg, rowend, srcsb, bufA, dis, b1, W2, bufB, N);
  k_agg2h<<<gN16, bn, 0, stream>>>(rowbeg, rowend, srcsb, bufB, dis, b2, Wc, bc, out, N);
}